// Round 5
// baseline (181.748 us; speedup 1.0000x reference)
//
#include <hip/hip_runtime.h>
#include <stdint.h>
#include <stddef.h>

// CliffordLinear as one bf16 GEMM:
//   out[b, o*8+l] = sum_{i,k} X[b, i*8+k] * Wt[o*8+l, i*8+k] + bias[o*8+l]
//   Wt[(o,l),(i,k)] = sum_j cayley[j,k,l] * W[o,i,j]
// M=8192, N=2048, K=2048. fp32 accumulate.
//
// R12: 32x32x16 MFMA + blocked-transposed operand layout.
// R8-R11 all plateaued at ~2550 cyc/slice = MFMA pipe (1242) + LDS pipe
// (~1150) SERIAL SUM, invariant across 4 different schedules -> shrink the
// LDS term instead of rescheduling it. 32x32x16 doubles FLOP per 16B/lane
// operand -> fragment reads halve (96->48 KB/slice) and the MFMA ceiling
// rises (2495 vs 2075 TF). The classic 32x32 killer (32-lane same-column
// reads = unswizzlable >=4-way conflict) is removed by changing the LAYOUT:
// operands stored as [K/8 k-octet][256 row][8 elems], so a 32x32 fragment
// read is two 512-B contiguous half-wave blocks -- zero conflicts, no
// swizzle. Staging becomes perfectly linear (src off == dst off == c*512)
// because prep emits X and folded-W in this blocked layout directly.
// Schedule: R9 ring skeleton (ring-4 slots, distance-3 stages, single
// barrier/window, counted vmcnt(6) never 0 in steady loop, ping-pong frag
// registers, setprio around MFMA, XCD swizzle).

typedef __bf16 bf16x4 __attribute__((ext_vector_type(4)));
typedef __bf16 bf16x8 __attribute__((ext_vector_type(8)));
typedef float  f32x4  __attribute__((ext_vector_type(4)));
typedef float  f32x16 __attribute__((ext_vector_type(16)));

#define BM 256
#define BN 256
#define NSLICES 64          // K=2048 / 32
#define SLOT 8192           // elems per slot (16 KB): [4 kg][256 rc][8]

__device__ __forceinline__ void async_copy16(void* lds_dst, const void* g_src) {
    __builtin_amdgcn_global_load_lds(
        (__attribute__((address_space(1))) void*)g_src,
        (__attribute__((address_space(3))) void*)lds_dst,
        16, 0, 0);
}

// ---------------- kernel 1: prep ------------------------------------------
// blocks [0, castBlocks): LDS-tiled transpose-cast of X (f32 row-major ->
//   bf16 blocked [M/256][K/8][256][8]); tile = 64 rows x 128 k.
// blocks [castBlocks, ...): fold Cayley into W, emitted in the same blocked
//   layout [N/256][K/8][256][8]; col-fast thread map for coalesced writes.
__global__ __launch_bounds__(256) void prep_kernel(
    const float* __restrict__ x, __bf16* __restrict__ Xb2,
    const float* __restrict__ W, const float* __restrict__ cayley,
    __bf16* __restrict__ Wt2, int M, int N, int K, int Cin, int castBlocks)
{
    if ((int)blockIdx.x < castBlocks) {
        __shared__ __bf16 T[16 * 520];   // [koL][64 rows][8], +8 pad per koL
        const int tk = blockIdx.x & 15;          // K/128 = 16 tiles
        const int tm = blockIdx.x >> 4;          // M/64 tiles
        const int row0 = tm * 64, k0 = tk * 128;
        #pragma unroll
        for (int it = 0; it < 8; ++it) {
            int idx = threadIdx.x + it * 256;    // 2048 f32x4 units
            int r = idx >> 5, kq = idx & 31;
            f32x4 v = *(const f32x4*)(x + (size_t)(row0 + r) * K + k0 + kq * 4);
            bf16x4 b;
            b[0] = (__bf16)v[0]; b[1] = (__bf16)v[1];
            b[2] = (__bf16)v[2]; b[3] = (__bf16)v[3];
            *(bf16x4*)&T[(kq >> 1) * 520 + r * 8 + (kq & 1) * 4] = b;
        }
        __syncthreads();
        const size_t obase = (size_t)(row0 >> 8) * K * 256
                           + (size_t)(k0 >> 3) * 2048
                           + (size_t)(row0 & 255) * 8;
        #pragma unroll
        for (int it = 0; it < 4; ++it) {
            int u = threadIdx.x + it * 256;      // 1024 output units
            int koL = u >> 6, rowi = u & 63;
            bf16x8 val = *(const bf16x8*)&T[koL * 520 + rowi * 8];
            *(bf16x8*)(Xb2 + obase + (size_t)koL * 2048 + rowi * 8) = val;
        }
        return;
    }
    // ---- fold
    __shared__ float Cay[512];
    for (int t = threadIdx.x; t < 512; t += 256) Cay[t] = cayley[t];
    __syncthreads();

    int flat = ((int)blockIdx.x - castBlocks) * 256 + threadIdx.x;
    if (flat >= Cin * N) return;
    int n = flat % N;          // col-fast: consecutive threads -> +16B writes
    int i = flat / N;
    int o = n >> 3, l = n & 7;

    const float* wrow = W + ((size_t)o * Cin + i) * 8;
    float w8[8];
    #pragma unroll
    for (int j = 0; j < 8; ++j) w8[j] = wrow[j];

    bf16x8 outv;
    #pragma unroll
    for (int k = 0; k < 8; ++k) {
        float s = 0.f;
        #pragma unroll
        for (int j = 0; j < 8; ++j) s += Cay[j * 64 + k * 8 + l] * w8[j];
        outv[k] = (__bf16)s;
    }
    *(bf16x8*)(Wt2 + (size_t)(n >> 8) * K * 256 + (size_t)i * 2048
                   + (n & 255) * 8) = outv;
}

// ---------------- kernel 2: bf16 GEMM, 32x32x16 MFMA ----------------------
// A2 : [M/256][K/8][256 rows][8] bf16 blocked-transposed
// B2 : [N/256][K/8][256 cols][8]
// C  : [M][N] fp32
// LDS slot (one 32-wide K-slice of A or B) = [4 kg][256 rc][8] = 16 KB.
// Fragment read (mt/nt, ks): lane l -> rc = base + (l&31), kg = ks*2+(l>>5):
// two 512-B contiguous half-wave blocks -> conflict-free, no swizzle.
// Staging chunk c (0..15): kg=c>>2, rows (c&3)*64+lane: src off == dst off
// == c*512 elems -> linear global_load_lds both sides.
__global__ __launch_bounds__(512, 2) void gemm_bt_kernel(
    const __bf16* __restrict__ A2,
    const __bf16* __restrict__ B2,
    const float*  __restrict__ bias,
    float* __restrict__ C,
    int M, int N, int K)
{
    __shared__ __align__(16) __bf16 As[4][SLOT];  // 4 x 16 KB
    __shared__ __align__(16) __bf16 Bs[4][SLOT];  // 4 x 16 KB

    const int tid  = threadIdx.x;
    const int wave = tid >> 6;    // 0..7
    const int lane = tid & 63;
    const int l31  = lane & 31;
    const int lhi  = lane >> 5;

    // --- XCD swizzle: 256 blocks, 8 XCDs; bijective since 256%8==0.
    const int bid = blockIdx.x;
    const int xcd = bid & 7;
    const int idx = bid >> 3;                 // 0..31
    const int mBase = (xcd * 4 + (idx & 3)) * BM;
    const int nBase = (idx >> 2) * BN;

    // --- staging: wave w owns chunks 2w, 2w+1 (1 KB each) of A and B slices.
    const int c0 = 2 * wave, c1 = 2 * wave + 1;
    const __bf16* gA0 = A2 + (size_t)mBase * K + c0 * 512 + lane * 8;
    const __bf16* gA1 = A2 + (size_t)mBase * K + c1 * 512 + lane * 8;
    const __bf16* gB0 = B2 + (size_t)nBase * K + c0 * 512 + lane * 8;
    const __bf16* gB1 = B2 + (size_t)nBase * K + c1 * 512 + lane * 8;
    const int dstA0 = c0 * 512, dstA1 = c1 * 512;

#define STAGE_A(slot, q) do {                                              \
        async_copy16(&As[slot][dstA0], gA0 + (size_t)(q) * 8192);          \
        async_copy16(&As[slot][dstA1], gA1 + (size_t)(q) * 8192);          \
    } while (0)
#define STAGE_B(slot, q) do {                                              \
        async_copy16(&Bs[slot][dstA0], gB0 + (size_t)(q) * 8192);          \
        async_copy16(&Bs[slot][dstA1], gB1 + (size_t)(q) * 8192);          \
    } while (0)

    // --- compute: wave (wm,wn) owns 128x64; 4x2 tiles of 32x32.
    const int wm = wave >> 2;     // 0..1
    const int wn = wave & 3;      // 0..3
    const __bf16* paBase = &As[0][lhi * 2048 + (wm * 128 + l31) * 8];
    const __bf16* pbBase = &Bs[0][lhi * 2048 + (wn * 64  + l31) * 8];
    // frag (mt, ks): + ks*4096 + mt*256 ; B: + ks*4096 + nt*256

    f32x16 acc[4][2] = {};
    bf16x8 a0A[4], b0A[2], a0B[4], b0B[2], af1[4], bf1[2];

    // --- prologue: stage slices 0,1,2 (A+B interleaved, 12 loads/thread).
    // vmcnt(8) -> A0,B0 landed. Barrier, pre-read slice-0 ks0 frags.
    STAGE_A(0, 0); STAGE_B(0, 0);
    STAGE_A(1, 1); STAGE_B(1, 1);
    STAGE_A(2, 2); STAGE_B(2, 2);
    asm volatile("s_waitcnt vmcnt(8)" ::: "memory");
    __builtin_amdgcn_s_barrier();

    #pragma unroll
    for (int j = 0; j < 4; ++j)
        a0A[j] = *(const bf16x8*)(paBase + j * 256);
    #pragma unroll
    for (int q = 0; q < 2; ++q)
        b0A[q] = *(const bf16x8*)(pbBase + q * 256);

    // One slice = two windows.
    //  h0: read ks1 frags (af1,bf1; slot c_) | stage A(s+3) | 8 MFMA ks0 on
    //      (A0F,B0F) | vmcnt(6): A(s+1),B(s+1) landed | barrier
    //  h1: read slice s+1 ks0 frags (slot n_) into (A0N,B0N) | stage B(s+3)
    //      | 8 MFMA ks1 on (af1,bf1) | barrier
#define SLICE_BODY(s_, c_, n_, A0F, B0F, A0N, B0N, DOA, DOB, DOPF, VM0)        \
    do {                                                                       \
        _Pragma("unroll")                                                      \
        for (int j = 0; j < 4; ++j)                                            \
            af1[j] = *(const bf16x8*)(paBase + (c_) * SLOT + 4096 + j * 256);  \
        _Pragma("unroll")                                                      \
        for (int q = 0; q < 2; ++q)                                            \
            bf1[q] = *(const bf16x8*)(pbBase + (c_) * SLOT + 4096 + q * 256);  \
        if (DOA) STAGE_A(((s_) + 3) & 3, (s_) + 3);                            \
        __builtin_amdgcn_s_setprio(1);                                         \
        _Pragma("unroll")                                                      \
        for (int j = 0; j < 4; ++j)                                            \
            _Pragma("unroll")                                                  \
            for (int q = 0; q < 2; ++q)                                        \
                acc[j][q] = __builtin_amdgcn_mfma_f32_32x32x16_bf16(           \
                    A0F[j], B0F[q], acc[j][q], 0, 0, 0);                       \
        __builtin_amdgcn_s_setprio(0);                                         \
        if (VM0) asm volatile("s_waitcnt vmcnt(0)" ::: "memory");              \
        else     asm volatile("s_waitcnt vmcnt(6)" ::: "memory");              \
        __builtin_amdgcn_s_barrier();                                          \
        if (DOPF) {                                                            \
            _Pragma("unroll")                                                  \
            for (int j = 0; j < 4; ++j)                                        \
                A0N[j] = *(const bf16x8*)(paBase + (n_) * SLOT + j * 256);     \
            _Pragma("unroll")                                                  \
            for (int q = 0; q < 2; ++q)                                        \
                B0N[q] = *(const bf16x8*)(pbBase + (n_) * SLOT + q * 256);     \
        }                                                                      \
        if (DOB) STAGE_B(((s_) + 3) & 3, (s_) + 3);                            \
        __builtin_amdgcn_s_setprio(1);                                         \
        _Pragma("unroll")                                                      \
        for (int j = 0; j < 4; ++j)                                            \
            _Pragma("unroll")                                                  \
            for (int q = 0; q < 2; ++q)                                        \
                acc[j][q] = __builtin_amdgcn_mfma_f32_32x32x16_bf16(           \
                    af1[j], bf1[q], acc[j][q], 0, 0, 0);                       \
        __builtin_amdgcn_s_setprio(0);                                         \
        __builtin_amdgcn_s_barrier();                                          \
    } while (0)

    // --- main loop: 60 slices (ring period 4 x reg ping-pong period 2).
    #pragma unroll 1
    for (int s4 = 0; s4 < 15; ++s4) {
        const int s = s4 * 4;
        SLICE_BODY(s + 0, 0, 1, a0A, b0A, a0B, b0B, true, true, true, false);
        SLICE_BODY(s + 1, 1, 2, a0B, b0B, a0A, b0A, true, true, true, false);
        SLICE_BODY(s + 2, 2, 3, a0A, b0A, a0B, b0B, true, true, true, false);
        SLICE_BODY(s + 3, 3, 0, a0B, b0B, a0A, b0A, true, true, true, false);
    }
    // --- tail: slices 60..63. Last stages at s=60 (A63,B63); vmcnt(0) from
    // s=61 (drains loads issued >=1 slice earlier); no prefetch at 63.
    SLICE_BODY(60, 0, 1, a0A, b0A, a0B, b0B, true,  true,  true,  false);
    SLICE_BODY(61, 1, 2, a0B, b0B, a0A, b0A, false, false, true,  true);
    SLICE_BODY(62, 2, 3, a0A, b0A, a0B, b0B, false, false, true,  true);
    SLICE_BODY(63, 3, 0, a0B, b0B, a0A, b0A, false, false, false, true);
    asm volatile("s_waitcnt vmcnt(0)" ::: "memory");

#undef SLICE_BODY
#undef STAGE_A
#undef STAGE_B

    // --- epilogue: 32x32 C/D layout: col = lane&31,
    // row = (reg&3) + 8*(reg>>2) + 4*(lane>>5)   [m74/m101 verified]
    float bv[2];
    #pragma unroll
    for (int q = 0; q < 2; ++q)
        bv[q] = bias[nBase + wn * 64 + q * 32 + l31];

    #pragma unroll
    for (int mt = 0; mt < 4; ++mt) {
        #pragma unroll
        for (int q = 0; q < 2; ++q) {
            const int col = nBase + wn * 64 + q * 32 + l31;
            #pragma unroll
            for (int r = 0; r < 16; ++r) {
                const int row = mBase + wm * 128 + mt * 32
                              + (r & 3) + 8 * (r >> 2) + 4 * lhi;
                C[(size_t)row * N + col] = acc[mt][q][r] + bv[q];
            }
        }
    }
}

extern "C" void kernel_launch(void* const* d_in, const int* in_sizes, int n_in,
                              void* d_out, int out_size, void* d_ws, size_t ws_size,
                              hipStream_t stream) {
    const float* x      = (const float*)d_in[0];  // [B][Cin][8]
    const float* weight = (const float*)d_in[1];  // [Cout][Cin][8]
    const float* bias   = (const float*)d_in[2];  // [Cout][8]
    const float* cayley = (const float*)d_in[3];  // [8][8][8]
    float* out = (float*)d_out;                   // [B][Cout][8]

    const int Cout = in_sizes[2] / 8;
    const int Cin  = in_sizes[1] / (Cout * 8);
    const int Bm   = in_sizes[0] / (Cin * 8);
    const int M = Bm;          // 8192
    const int N = Cout * 8;    // 2048
    const int K = Cin * 8;     // 2048

    __bf16* Xb2 = (__bf16*)d_ws;                               // 32 MB blocked
    __bf16* Wt2 = (__bf16*)((char*)d_ws + (size_t)M * K * 2);  // 8 MB blocked

    // 1) prep: transpose-cast X + fold Cayley, one dispatch
    int castBlocks = (M / 64) * (K / 128);              // 2048
    int foldBlocks = (Cin * N + 255) / 256;             // 2048
    prep_kernel<<<castBlocks + foldBlocks, 256, 0, stream>>>(
        x, Xb2, weight, cayley, Wt2, M, N, K, Cin, castBlocks);

    // 2) GEMM: 256x256 tiles, 32 x 8 = 256 blocks, 512 threads (8 waves)
    int grid = (M / BM) * (N / BN);
    gemm_bt_kernel<<<grid, 512, 0, stream>>>(Xb2, Wt2, bias, out, M, N, K);
}